// Round 12
// baseline (195.461 us; speedup 1.0000x reference)
//
#include <hip/hip_runtime.h>
#include <hip/hip_bf16.h>
#include <math.h>

#define B_N 2048
#define T_N 8192
#define NFFT 4096
#define TF_LEN 4097
#define TOPK 5
#define KSPLIT 4
#define GBK 64

// padded LDS index for float2 Zs array (v6): n + (n>>4) + (n>>8) spreads the
// digit-reversed scatter's 256/512-multiples across bank-pairs; FFT passes
// stay <=2-way. Strictly increasing -> bijective.
#define ZIDX(n) ((n) + ((n) >> 4) + ((n) >> 8))
#define ZPAD (NFFT + (NFFT >> 4) + (NFFT >> 8))  // 4368 float2 slots

typedef float f32x4 __attribute__((ext_vector_type(4)));
typedef __bf16 bf16x8 __attribute__((ext_vector_type(8)));
typedef unsigned short ushort_t;

__device__ __forceinline__ void gload_lds16(const ushort_t* g, ushort_t* l) {
    __builtin_amdgcn_global_load_lds(
        (const __attribute__((address_space(1))) void*)g,
        (__attribute__((address_space(3))) void*)l,
        16, 0, 0);
}

__device__ __forceinline__ float wave_reduce_sum(float v) {
    for (int o = 32; o >= 1; o >>= 1) v += __shfl_xor(v, o, 64);
    return v;
}
__device__ __forceinline__ float wave_reduce_max(float v) {
    for (int o = 32; o >= 1; o >>= 1) v = fmaxf(v, __shfl_xor(v, o, 64));
    return v;
}

__device__ __forceinline__ ushort_t f2bf(float x) {
    __hip_bfloat16 h = __float2bfloat16(x);
    return *reinterpret_cast<ushort_t*>(&h);
}

// native HW trig: input in REVOLUTIONS; cis_rev(r) = (cos(2*pi*r), sin(2*pi*r))
__device__ __forceinline__ float2 cis_rev(float rev) {
    return make_float2(__builtin_amdgcn_cosf(rev), __builtin_amdgcn_sinf(rev));
}
__device__ __forceinline__ float2 cmulf(float2 a, float2 b) {
    return make_float2(a.x * b.x - a.y * b.y, a.x * b.y + a.y * b.x);
}

// binary-power twiddle table: tw[r] = w1^r, depth 4 (was a 15-deep chain).
// All indices static -> registers.
__device__ __forceinline__ void gen_pows(float2 w1, float2 tw[16]) {
    tw[1] = w1;
    tw[2] = cmulf(w1, w1);
    tw[3] = cmulf(tw[2], w1);
    tw[4] = cmulf(tw[2], tw[2]);
    tw[5] = cmulf(tw[4], w1);
    tw[6] = cmulf(tw[4], tw[2]);
    tw[7] = cmulf(tw[4], tw[3]);
    tw[8] = cmulf(tw[4], tw[4]);
    tw[9] = cmulf(tw[8], w1);
    tw[10] = cmulf(tw[8], tw[2]);
    tw[11] = cmulf(tw[8], tw[3]);
    tw[12] = cmulf(tw[8], tw[4]);
    tw[13] = cmulf(tw[8], tw[5]);
    tw[14] = cmulf(tw[8], tw[6]);
    tw[15] = cmulf(tw[8], tw[7]);
}

// ---------------- init: zero acc (incl. acc[3] = done counter) ----------------
__global__ __launch_bounds__(256) void init_kernel(float* acc, float* Cpart, int nzbuf) {
    if (blockIdx.x == 0 && threadIdx.x < 4) acc[threadIdx.x] = 0.0f;
    if (nzbuf == 1) {
        size_t idx = ((size_t)blockIdx.x * 256 + threadIdx.x) * 4;
        *reinterpret_cast<f32x4*>(&Cpart[idx]) = (f32x4){0.f, 0.f, 0.f, 0.f};
    }
}

// ---------------- DFT16 in registers (two radix-4 levels) ----------------
__device__ __forceinline__ void dft4(float2 x0, float2 x1, float2 x2, float2 x3,
                                     float2* y0, float2* y1, float2* y2, float2* y3) {
    float2 t0 = make_float2(x0.x + x2.x, x0.y + x2.y);
    float2 t1 = make_float2(x0.x - x2.x, x0.y - x2.y);
    float2 t2 = make_float2(x1.x + x3.x, x1.y + x3.y);
    float2 t3 = make_float2(x1.x - x3.x, x1.y - x3.y);
    *y0 = make_float2(t0.x + t2.x, t0.y + t2.y);
    *y2 = make_float2(t0.x - t2.x, t0.y - t2.y);
    *y1 = make_float2(t1.x + t3.y, t1.y - t3.x);   // t1 + (-i)*t3
    *y3 = make_float2(t1.x - t3.y, t1.y + t3.x);   // t1 - (-i)*t3
}

__device__ __forceinline__ void dft16(float2 X[16]) {
    float2 G[16];
    dft4(X[0], X[4], X[8],  X[12], &G[0],  &G[1],  &G[2],  &G[3]);
    dft4(X[1], X[5], X[9],  X[13], &G[4],  &G[5],  &G[6],  &G[7]);
    dft4(X[2], X[6], X[10], X[14], &G[8],  &G[9],  &G[10], &G[11]);
    dft4(X[3], X[7], X[11], X[15], &G[12], &G[13], &G[14], &G[15]);
    const float C1 = 0.9238795325112867f, S1 = 0.3826834323650898f;
    const float R2 = 0.7071067811865476f;
    G[5]  = cmulf(G[5],  make_float2(C1, -S1));   // W^1
    G[6]  = cmulf(G[6],  make_float2(R2, -R2));   // W^2
    G[7]  = cmulf(G[7],  make_float2(S1, -C1));   // W^3
    G[9]  = cmulf(G[9],  make_float2(R2, -R2));   // W^2
    { float2 g = G[10]; G[10] = make_float2(g.y, -g.x); }  // W^4 = -i
    G[11] = cmulf(G[11], make_float2(-R2, -R2));  // W^6
    G[13] = cmulf(G[13], make_float2(S1, -C1));   // W^3
    G[14] = cmulf(G[14], make_float2(-R2, -R2));  // W^6
    G[15] = cmulf(G[15], make_float2(-C1, S1));   // W^9
    dft4(G[0], G[4], G[8],  G[12], &X[0], &X[4], &X[8],  &X[12]);
    dft4(G[1], G[5], G[9],  G[13], &X[1], &X[5], &X[9],  &X[13]);
    dft4(G[2], G[6], G[10], G[14], &X[2], &X[6], &X[10], &X[14]);
    dft4(G[3], G[7], G[11], G[15], &X[3], &X[7], &X[11], &X[15]);
}

// rfft bin from packed-complex spectrum (exact path, used for top bins)
__device__ __forceinline__ void rfft_bin(const float2* Zs, int k, float* orr, float* oi) {
    int kk = k & (NFFT - 1);
    int nk = (NFFT - k) & (NFFT - 1);
    float2 zk = Zs[ZIDX(kk)], znk = Zs[ZIDX(nk)];
    float xer = 0.5f * (zk.x + znk.x);
    float xei = 0.5f * (zk.y - znk.y);
    float xo_r = 0.5f * (zk.y + znk.y);
    float xo_i = -0.5f * (zk.x - znk.x);
    float2 w = cis_rev((float)k * (-1.0f / (float)T_N));
    *orr = xer + w.x * xo_r - w.y * xo_i;
    *oi = xei + w.x * xo_i + w.y * xo_r;
}

// ---------------- fused per-row kernel: prep + ashift + phase ----------------
// v6 (round-9/11 best, 179.2us total): ZIDX bank-spread pad, binary-power
// twiddles, constant-rotor amp, register av[16] + 1-barrier top-5,
// shuffle-Bbf, P_c-decomposed direct DFT. Latency-chain floor ~100us:
// proven insensitive to occupancy/barriers/bank-conflicts (rounds 5-9).
__global__ __launch_bounds__(256) void fused_row_kernel(const float* __restrict__ inp,
                                                        const float* __restrict__ tgt,
                                                        ushort_t* __restrict__ Abf,
                                                        ushort_t* __restrict__ Bbf,
                                                        float* acc) {
    __shared__ float2 Zs[ZPAD];
    __shared__ float red[12];
    __shared__ float wv[2][4];
    __shared__ int wi[2][4];
    __shared__ float2 tgtF[TOPK];
    __shared__ float rscratch[64];

    int b = blockIdx.x;
    int tid = threadIdx.x;
    int lane = tid & 63, wid = tid >> 6;
    const float* tp = tgt + (size_t)b * T_N;
    const float* ip = inp + (size_t)b * T_N;
    ushort_t* Ab = Abf + (size_t)b * T_N;
    ushort_t* Bb = Bbf + (size_t)b * T_N;

    // ---- load tgt: regs + Abf + digit-reversed complex scatter into Zs ----
    float4 trv[8];
#pragma unroll
    for (int i = 0; i < 8; i++) {
        int q = tid + 256 * i;
        trv[i] = *reinterpret_cast<const float4*>(&tp[4 * q]);
        ushort4 ua;
        ua.x = f2bf(trv[i].x); ua.y = f2bf(trv[i].y);
        ua.z = f2bf(trv[i].z); ua.w = f2bf(trv[i].w);
        *reinterpret_cast<ushort4*>(&Ab[4 * q]) = ua;
        int m0 = 2 * q, m1 = 2 * q + 1;
        int p0 = ((m0 & 15) << 8) | (m0 & 0x0F0) | (m0 >> 8);
        int p1 = ((m1 & 15) << 8) | (m1 & 0x0F0) | (m1 >> 8);
        Zs[ZIDX(p0)] = make_float2(trv[i].x, trv[i].y);
        Zs[ZIDX(p1)] = make_float2(trv[i].z, trv[i].w);
    }

    // ---- load inp; d = inp - tgt; Bbf via lane-reversal shuffle ----
    float4 irv[8], dv[8];
#pragma unroll
    for (int i = 0; i < 8; i++) {
        int q = tid + 256 * i;
        irv[i] = *reinterpret_cast<const float4*>(&ip[4 * q]);
        dv[i] = make_float4(irv[i].x - trv[i].x, irv[i].y - trv[i].y,
                            irv[i].z - trv[i].z, irv[i].w - trv[i].w);
        ushort4 ub;
        ub.x = f2bf(-dv[i].w); ub.y = f2bf(-dv[i].z);
        ub.z = f2bf(-dv[i].y); ub.w = f2bf(-dv[i].x);
        uint2 p = *reinterpret_cast<uint2*>(&ub);
        p.x = __shfl_xor(p.x, 63, 64);
        p.y = __shfl_xor(p.y, 63, 64);
        int o = lane + 64 * (31 - wid - 4 * i);
        *reinterpret_cast<uint2*>(&Bb[4 * o]) = p;
    }

    // ---- ashift from d registers (3 barriers via disjoint red slots) ----
    {
        float lmax = -1e30f;
#pragma unroll
        for (int i = 0; i < 8; i++)
            lmax = fmaxf(lmax, fmaxf(fmaxf(dv[i].x, dv[i].y), fmaxf(dv[i].z, dv[i].w)));
        lmax = wave_reduce_max(lmax);
        if (lane == 0) red[wid] = lmax;
        __syncthreads();  // #1: also orders the Zs scatter before FFT pass 0
        float mx = fmaxf(fmaxf(red[0], red[1]), fmaxf(red[2], red[3]));
        float lsum = 0.0f;
#pragma unroll
        for (int i = 0; i < 8; i++) {
            dv[i].x = __expf(dv[i].x - mx);
            dv[i].y = __expf(dv[i].y - mx);
            dv[i].z = __expf(dv[i].z - mx);
            dv[i].w = __expf(dv[i].w - mx);
            lsum += (dv[i].x + dv[i].y) + (dv[i].z + dv[i].w);
        }
        lsum = wave_reduce_sum(lsum);
        if (lane == 0) red[4 + wid] = lsum;
        __syncthreads();  // #2
        float Z = (red[4] + red[5]) + (red[6] + red[7]);
        float inv = 1.0f / Z;
        const float u = 1.0f / (float)T_N;
        float labs = 0.0f;
#pragma unroll
        for (int i = 0; i < 8; i++) {
            labs += fabsf(u - dv[i].x * inv) + fabsf(u - dv[i].y * inv) +
                    fabsf(u - dv[i].z * inv) + fabsf(u - dv[i].w * inv);
        }
        labs = wave_reduce_sum(labs);
        if (lane == 0) red[8 + wid] = labs;
        __syncthreads();  // #3
        if (tid == 0)
            atomicAdd(acc + 0, (red[8] + red[9]) + (red[10] + red[11]));
    }
    // no extra barrier: sync #3 ordered all scatter writes; pass 0 below only
    // reads/writes thread-owned runs after that sync.

    // ---- FFT: 3 radix-16 passes, in place (digit-reversed input) ----
    {  // pass 0: base 16t, stride 1, no twiddle
        float2 X[16];
        int base = tid * 16;
#pragma unroll
        for (int r = 0; r < 16; r++) X[r] = Zs[ZIDX(base + r)];
        dft16(X);
#pragma unroll
        for (int r = 0; r < 16; r++) Zs[ZIDX(base + r)] = X[r];
    }
    __syncthreads();
    {  // pass 1: base = (t>>4)*256 + (t&15), stride 16, twiddle W_256^{j r}
        float2 X[16];
        int j = tid & 15;
        int base = (tid >> 4) * 256 + j;
#pragma unroll
        for (int r = 0; r < 16; r++) X[r] = Zs[ZIDX(base + 16 * r)];
        float2 tw[16];
        gen_pows(cis_rev(-(float)j * (1.0f / 256.0f)), tw);
#pragma unroll
        for (int r = 1; r < 16; r++) X[r] = cmulf(X[r], tw[r]);
        dft16(X);
#pragma unroll
        for (int r = 0; r < 16; r++) Zs[ZIDX(base + 16 * r)] = X[r];
    }
    __syncthreads();
    {  // pass 2: base = t, stride 256, twiddle W_4096^{t r}
        float2 X[16];
#pragma unroll
        for (int r = 0; r < 16; r++) X[r] = Zs[ZIDX(tid + 256 * r)];
        float2 tw[16];
        gen_pows(cis_rev(-(float)tid * (1.0f / 4096.0f)), tw);
#pragma unroll
        for (int r = 1; r < 16; r++) X[r] = cmulf(X[r], tw[r]);
        dft16(X);
#pragma unroll
        for (int r = 0; r < 16; r++) Zs[ZIDX(tid + 256 * r)] = X[r];
    }
    __syncthreads();

    // ---- amplitude^2 of rfft bins -> REGISTERS ----
    // rot_i = rot0 * cis(-i/32): compile-time constants, no serial chain.
    float av[16];
    float aN = -3.0f;  // Nyquist bin 4096, valid on tid 0 only
    {
        const float CC[16] = {
            1.0f, 0.9807852804032304f, 0.9238795325112867f, 0.8314696123025452f,
            0.7071067811865476f, 0.5555702330196022f, 0.3826834323650898f,
            0.1950903220161283f, 0.0f, -0.1950903220161283f, -0.3826834323650898f,
            -0.5555702330196022f, -0.7071067811865476f, -0.8314696123025452f,
            -0.9238795325112867f, -0.9807852804032304f};
        const float SS[16] = {
            0.0f, -0.1950903220161283f, -0.3826834323650898f, -0.5555702330196022f,
            -0.7071067811865476f, -0.8314696123025452f, -0.9238795325112867f,
            -0.9807852804032304f, -1.0f, -0.9807852804032304f, -0.9238795325112867f,
            -0.8314696123025452f, -0.7071067811865476f, -0.5555702330196022f,
            -0.3826834323650898f, -0.1950903220161283f};
        float2 rot0 = cis_rev(-(float)tid * (1.0f / (float)T_N));
#pragma unroll
        for (int i = 0; i < 16; i++) {
            int k = tid + 256 * i;
            if (i == 0 && tid == 0) {
                av[i] = -1.0f;  // DC excluded (reference zeroes bin 0)
            } else {
                float2 rot = cmulf(rot0, make_float2(CC[i], SS[i]));
                int nk = (NFFT - k) & (NFFT - 1);
                float2 zk = Zs[ZIDX(k & (NFFT - 1))], znk = Zs[ZIDX(nk)];
                float xer = 0.5f * (zk.x + znk.x);
                float xei = 0.5f * (zk.y - znk.y);
                float xo_r = 0.5f * (zk.y + znk.y);
                float xo_i = -0.5f * (zk.x - znk.x);
                float xr = xer + rot.x * xo_r - rot.y * xo_i;
                float xi = xei + rot.x * xo_i + rot.y * xo_r;
                av[i] = xr * xr + xi * xi;
            }
        }
        if (tid == 0) {  // Nyquist bin 4096
            float2 z0 = Zs[ZIDX(0)];
            float v = z0.x - z0.y;
            aN = v * v;
        }
    }

    // ---- top-5: 5 argmax rounds over registers, 1 barrier/round ----
    int fqa[TOPK];
#pragma unroll
    for (int r = 0; r < TOPK; r++) {
        float bv = -3.0f;
        int bi = TF_LEN;
#pragma unroll
        for (int i = 0; i < 16; i++) {
            float a = av[i];
            if (a > bv) { bv = a; bi = tid + 256 * i; }
        }
        if (aN > bv) { bv = aN; bi = 4096; }
        for (int o = 1; o < 64; o <<= 1) {
            float ov = __shfl_xor(bv, o, 64);
            int oi = __shfl_xor(bi, o, 64);
            if (ov > bv || (ov == bv && oi < bi)) { bv = ov; bi = oi; }
        }
        if (lane == 0) { wv[r & 1][wid] = bv; wi[r & 1][wid] = bi; }
        __syncthreads();
        float fv = wv[r & 1][0];
        int fi = wi[r & 1][0];
#pragma unroll
        for (int w2 = 1; w2 < 4; w2++) {
            float cv = wv[r & 1][w2];
            int ci = wi[r & 1][w2];
            if (cv > fv || (cv == fv && ci < fi)) { fv = cv; fi = ci; }
        }
        fqa[r] = fi;
        if (fi == 4096) {
            if (tid == 0) aN = -2.0f;
        } else if ((fi & 255) == tid) {
            int slot = fi >> 8;
#pragma unroll
            for (int i = 0; i < 16; i++)
                if (i == slot) av[i] = -2.0f;  // static index (no scratch spill)
        }
    }

    // ---- exact target spectrum at top bins ----
    if (tid < TOPK) {
        int myf = fqa[0];
        if (tid == 1) myf = fqa[1];
        if (tid == 2) myf = fqa[2];
        if (tid == 3) myf = fqa[3];
        if (tid == 4) myf = fqa[4];
        float xr, xi;
        rfft_bin(Zs, myf, &xr, &xi);
        tgtF[tid] = make_float2(xr, xi);
    }
    __syncthreads();

    // ---- direct DFT of input at 5 bins: P_c decomposition ----
    float2 cur[TOPK], wr[TOPK];
    float pre[TOPK][4], pim[TOPK][4];
#pragma unroll
    for (int q = 0; q < TOPK; q++) {
        int f = fqa[q];
        cur[q] = cis_rev(-(float)((f * 4 * tid) & (T_N - 1)) * (1.0f / (float)T_N));
        wr[q] = cis_rev(-(float)((f * 1024) & (T_N - 1)) * (1.0f / (float)T_N));
#pragma unroll
        for (int c = 0; c < 4; c++) { pre[q][c] = 0.0f; pim[q][c] = 0.0f; }
    }
    float E = 0.0f, sev = 0.0f, sod = 0.0f;
#pragma unroll
    for (int i = 0; i < 8; i++) {
        float4 v = irv[i];
        E = fmaf(v.x, v.x, E); sev += v.x;
        E = fmaf(v.y, v.y, E); sod += v.y;
        E = fmaf(v.z, v.z, E); sev += v.z;
        E = fmaf(v.w, v.w, E); sod += v.w;
#pragma unroll
        for (int q = 0; q < TOPK; q++) {
            pre[q][0] = fmaf(v.x, cur[q].x, pre[q][0]);
            pim[q][0] = fmaf(v.x, cur[q].y, pim[q][0]);
            pre[q][1] = fmaf(v.y, cur[q].x, pre[q][1]);
            pim[q][1] = fmaf(v.y, cur[q].y, pim[q][1]);
            pre[q][2] = fmaf(v.z, cur[q].x, pre[q][2]);
            pim[q][2] = fmaf(v.z, cur[q].y, pim[q][2]);
            pre[q][3] = fmaf(v.w, cur[q].x, pre[q][3]);
            pim[q][3] = fmaf(v.w, cur[q].y, pim[q][3]);
            cur[q] = cmulf(cur[q], wr[q]);
        }
    }
    // finalize: res = P0 + W*(P1 + W*(P2 + W*P3)), W = W_8192^f
    float re[TOPK], im[TOPK];
#pragma unroll
    for (int q = 0; q < TOPK; q++) {
        float2 wcq = cis_rev(-(float)fqa[q] * (1.0f / (float)T_N));
        float tr = pre[q][3], ti = pim[q][3];
        float ur = pre[q][2] + (wcq.x * tr - wcq.y * ti);
        float ui = pim[q][2] + (wcq.x * ti + wcq.y * tr);
        float vr = pre[q][1] + (wcq.x * ur - wcq.y * ui);
        float vi = pim[q][1] + (wcq.x * ui + wcq.y * ur);
        re[q] = pre[q][0] + (wcq.x * vr - wcq.y * vi);
        im[q] = pim[q][0] + (wcq.x * vi + wcq.y * vr);
    }

    // ---- block-reduce the 13 scalars and finalize ----
    float vals[13] = {re[0], im[0], re[1], im[1], re[2], im[2], re[3], im[3],
                      re[4], im[4], E, sev + sod, sev - sod};
#pragma unroll
    for (int i = 0; i < 13; i++) {
        float v = wave_reduce_sum(vals[i]);
        if (lane == 0) rscratch[wid * 13 + i] = v;
    }
    __syncthreads();
    if (tid == 0) {
        float tot[13];
        for (int i = 0; i < 13; i++)
            tot[i] = rscratch[i] + rscratch[13 + i] + rscratch[26 + i] + rscratch[39 + i];
        float dsum = 0, isum = 0;
        for (int q = 0; q < TOPK; q++) {
            float rr = tot[2 * q], ii = tot[2 * q + 1];
            float dr = tgtF[q].x - rr, di = tgtF[q].y - ii;
            dsum += dr * dr + di * di;
            isum += rr * rr + ii * ii;
        }
        float Ee = tot[10], X0v = tot[11], Xhv = tot[12];
        float S_all = 0.5f * ((float)T_N * Ee + X0v * X0v + Xhv * Xhv);
        float val = sqrtf(dsum) + sqrtf(fmaxf(S_all - isum, 0.0f));
        atomicAdd(acc + 1, val);
    }
}

// ---------------- GEMM: 256x256 tile, 8-phase counted-vmcnt schedule ----------------
// m201 template port (verified rounds 4-9). KSPLIT=4 plain-stored partials.
// NOTE (round 10): do NOT fold absum into this kernel's epilogue — at
// 1 block/CU all 256 blocks run in lockstep, so the "overlapped" reduction
// becomes a 64-block serial tail with threadfence-poisoned caches (273us).
__global__ __launch_bounds__(512, 2) void gemm_kernel(const ushort_t* __restrict__ A,
                                                      const ushort_t* __restrict__ Bm,
                                                      float* __restrict__ Cpart,
                                                      int nzbuf) {
    __shared__ __align__(16) ushort_t lds[2][4][128 * 64];
    int tid = threadIdx.x;
    int bid = blockIdx.x;
    int swz = ((bid & 7) << 5) | (bid >> 3);   // bijective on [0,256): XCD = bid&7
    int bx = swz & 7, by = (swz >> 3) & 7, bz = swz >> 6;
    int row0 = bx * 256, col0 = by * 256;
    const int KC = T_N / KSPLIT;   // 2048
    const int NT = KC / GBK;       // 32
    const int NIT = NT / 2;        // 16
    int kbase = bz * KC;

    int w = tid >> 6, lane = tid & 63;
    int wm = w >> 2, wn = w & 3;   // 2M x 4N waves
    int lr = lane & 15, kq = lane >> 4;

    f32x4 accf[8][4];
#pragma unroll
    for (int mi = 0; mi < 8; mi++)
#pragma unroll
        for (int ni = 0; ni < 4; ni++) accf[mi][ni] = (f32x4){0.f, 0.f, 0.f, 0.f};

    // staging: thread -> (row-in-subhalf, inverse-swizzled col-block)
    int strow = tid >> 3;                 // 0..63
    int scb = (tid & 7) ^ (strow & 7);    // logical 16B col-block
    const ushort_t* gA0 = A + (size_t)(row0 + strow) * T_N + kbase + scb * 8;
    const ushort_t* gA1 = A + (size_t)(row0 + 128 + strow) * T_N + kbase + scb * 8;
    const ushort_t* gB0 = Bm + (size_t)(col0 + strow) * T_N + kbase + scb * 8;
    const ushort_t* gB1 = Bm + (size_t)(col0 + 128 + strow) * T_N + kbase + scb * 8;
    const size_t SUB = (size_t)64 * T_N;  // +64 rows

    // swizzled ds_read bases (ushort units): row*64 + ((cb ^ (row&7))<<3)
    int rb0 = lr * 64 + ((kq ^ (lr & 7)) << 3);        // k-slice 0 (cb = kq)
    int rb1 = lr * 64 + (((4 + kq) ^ (lr & 7)) << 3);  // k-slice 1 (cb = 4+kq)

#define SA_(s, buf, kt)                                                        \
    do {                                                                       \
        gload_lds16(gA0 + (s) * SUB + (size_t)(kt) * GBK, &lds[buf][0][(s) * 4096 + tid * 8]); \
        gload_lds16(gA1 + (s) * SUB + (size_t)(kt) * GBK, &lds[buf][1][(s) * 4096 + tid * 8]); \
    } while (0)
#define SB_(rg, buf, kt)                                                       \
    do {                                                                       \
        const ushort_t* g_ = ((rg) == 2) ? gB0 : gB1;                          \
        gload_lds16(g_ + (size_t)(kt) * GBK, &lds[buf][rg][tid * 8]);          \
        gload_lds16(g_ + SUB + (size_t)(kt) * GBK, &lds[buf][rg][4096 + tid * 8]); \
    } while (0)

#define PHASE(BUF, QM, QN, VMN, STAGE_STMT)                                    \
    do {                                                                       \
        asm volatile("s_waitcnt vmcnt(" #VMN ")" ::: "memory");                \
        const ushort_t* Ab_ = &lds[BUF][wm][0];                                \
        const ushort_t* Bb_ = &lds[BUF][2 + (wn >> 1)][(wn & 1) * 4096];       \
        bf16x8 a_[4][2], b_[2][2];                                             \
        _Pragma("unroll") for (int m_ = 0; m_ < 4; m_++) {                     \
            a_[m_][0] = *reinterpret_cast<const bf16x8*>(Ab_ + (QM) * 4096 + m_ * 1024 + rb0); \
            a_[m_][1] = *reinterpret_cast<const bf16x8*>(Ab_ + (QM) * 4096 + m_ * 1024 + rb1); \
        }                                                                      \
        _Pragma("unroll") for (int n_ = 0; n_ < 2; n_++) {                     \
            b_[n_][0] = *reinterpret_cast<const bf16x8*>(Bb_ + (QN) * 2048 + n_ * 1024 + rb0); \
            b_[n_][1] = *reinterpret_cast<const bf16x8*>(Bb_ + (QN) * 2048 + n_ * 1024 + rb1); \
        }                                                                      \
        STAGE_STMT;                                                            \
        __builtin_amdgcn_s_barrier();                                          \
        __builtin_amdgcn_s_setprio(1);                                         \
        _Pragma("unroll") for (int m_ = 0; m_ < 4; m_++)                       \
        _Pragma("unroll") for (int n_ = 0; n_ < 2; n_++) {                     \
            accf[(QM) * 4 + m_][(QN) * 2 + n_] = __builtin_amdgcn_mfma_f32_16x16x32_bf16( \
                a_[m_][0], b_[n_][0], accf[(QM) * 4 + m_][(QN) * 2 + n_], 0, 0, 0); \
            accf[(QM) * 4 + m_][(QN) * 2 + n_] = __builtin_amdgcn_mfma_f32_16x16x32_bf16( \
                a_[m_][1], b_[n_][1], accf[(QM) * 4 + m_][(QN) * 2 + n_], 0, 0, 0); \
        }                                                                      \
        __builtin_amdgcn_s_setprio(0);                                         \
        __builtin_amdgcn_s_barrier();                                          \
    } while (0)

    // prologue: tile0 fully (A.s0, A.s1, B0, B1) + tile1.A.s0; drain to 2.
    SA_(0, 0, 0);
    SA_(1, 0, 0);
    SB_(2, 0, 0);
    SB_(3, 0, 0);
    SA_(0, 1, 1);
    asm volatile("s_waitcnt vmcnt(2)" ::: "memory");
    __builtin_amdgcn_s_barrier();

    for (int it = 0; it < NIT; ++it) {
        int kt1 = 2 * it + 1;
        int te = (2 * it + 2 < NT) ? 2 * it + 2 : 2 * it;  // even tile (buf0)
        int to = (kt1 + 2 < NT) ? kt1 + 2 : kt1;           // odd tile (buf1)
        PHASE(0, 0, 0, 4, SB_(3, 1, kt1));
        PHASE(0, 0, 1, 4, SB_(2, 1, kt1));
        PHASE(0, 1, 0, 6, SA_(0, 0, te));
        PHASE(0, 1, 1, 2, SA_(1, 1, kt1));
        PHASE(1, 0, 0, 4, SB_(3, 0, te));
        PHASE(1, 0, 1, 2, SB_(2, 0, te));
        PHASE(1, 1, 0, 4, SA_(1, 0, te));
        PHASE(1, 1, 1, 2, SA_(0, 1, to));
    }
#undef PHASE
#undef SA_
#undef SB_

    // epilogue: store partial tile (plain stores; atomic fallback if nzbuf==1)
    int crow = row0 + wm * 128 + (lane >> 4) * 4;
    int ccol = col0 + wn * 64 + lr;
    if (nzbuf == 4) {
        float* Cp = Cpart + (size_t)bz * ((size_t)B_N * B_N);
#pragma unroll
        for (int mi = 0; mi < 8; mi++)
#pragma unroll
            for (int ni = 0; ni < 4; ni++)
#pragma unroll
                for (int r = 0; r < 4; r++)
                    Cp[(size_t)(crow + mi * 16 + r) * B_N + ccol + ni * 16] =
                        accf[mi][ni][r];
    } else {
#pragma unroll
        for (int mi = 0; mi < 8; mi++)
#pragma unroll
            for (int ni = 0; ni < 4; ni++)
#pragma unroll
                for (int r = 0; r < 4; r++)
                    atomicAdd(&Cpart[(size_t)(crow + mi * 16 + r) * B_N + ccol + ni * 16],
                              accf[mi][ni][r]);
    }
}

// ---------------- abs-reduce of summed partials + fused combine ----------------
// v7: the last of the 1024 blocks (done-counter in acc[3]) computes the final
// combine and writes out[0] -- removes the separate combine_kernel launch.
// acc[0]/acc[1] were written by earlier kernels (kernel-boundary visible);
// acc[2] is read via atomicAdd(+0) after an acquire threadfence.
__global__ __launch_bounds__(256) void absum_kernel(const float* __restrict__ C,
                                                    float* acc, float* out, int nzbuf) {
    __shared__ float sred[4];
    int tid = threadIdx.x;
    int lane = tid & 63, wid = tid >> 6;
    const size_t NN = (size_t)B_N * B_N;
    size_t base = (size_t)blockIdx.x * 4096;  // 1024 blocks x 4096 floats
    float s = 0.0f;
#pragma unroll
    for (int i = 0; i < 4; i++) {
        size_t idx = base + (size_t)(tid + 256 * i) * 4;
        f32x4 v = *reinterpret_cast<const f32x4*>(&C[idx]);
        if (nzbuf == 4) {
            v += *reinterpret_cast<const f32x4*>(&C[NN + idx]);
            v += *reinterpret_cast<const f32x4*>(&C[2 * NN + idx]);
            v += *reinterpret_cast<const f32x4*>(&C[3 * NN + idx]);
        }
        s += fabsf(v.x) + fabsf(v.y) + fabsf(v.z) + fabsf(v.w);
    }
    s = wave_reduce_sum(s);
    if (lane == 0) sred[wid] = s;
    __syncthreads();
    if (tid == 0) {
        atomicAdd(acc + 2, sred[0] + sred[1] + sred[2] + sred[3]);
        __threadfence();  // release my acc[2] contribution before the bump
        unsigned prev = atomicAdd(reinterpret_cast<unsigned*>(acc) + 3, 1u);
        if (prev == 1023u) {  // last arriver: all acc[2] adds are ordered before
            __threadfence();  // acquire
            float am = atomicAdd(acc + 2, 0.0f) / ((float)B_N * (float)B_N);
            float ash = acc[0] / (float)B_N;
            float ph = acc[1] / (float)B_N;
            out[0] = 0.5f * ash + 0.5f * ph + 0.01f * am;
        }
    }
}

extern "C" void kernel_launch(void* const* d_in, const int* in_sizes, int n_in,
                              void* d_out, int out_size, void* d_ws, size_t ws_size,
                              hipStream_t stream) {
    const float* inp = (const float*)d_in[0];
    const float* tgt = (const float*)d_in[1];
    float* acc = (float*)d_ws;
    ushort_t* Abf = (ushort_t*)((char*)d_ws + 256);
    ushort_t* Bbf = Abf + (size_t)B_N * T_N;
    float* Cpart = (float*)(Bbf + (size_t)B_N * T_N);
    float* out = (float*)d_out;

    size_t need4 = 256 + 2 * (size_t)B_N * T_N * sizeof(ushort_t)
                 + (size_t)KSPLIT * (size_t)B_N * B_N * sizeof(float);
    int nzbuf = (ws_size >= need4) ? 4 : 1;

    hipLaunchKernelGGL(init_kernel, dim3(nzbuf == 1 ? 4096 : 1), dim3(256), 0, stream,
                       acc, Cpart, nzbuf);
    hipLaunchKernelGGL(fused_row_kernel, dim3(B_N), dim3(256), 0, stream,
                       inp, tgt, Abf, Bbf, acc);
    hipLaunchKernelGGL(gemm_kernel, dim3(256), dim3(512), 0, stream,
                       Abf, Bbf, Cpart, nzbuf);
    hipLaunchKernelGGL(absum_kernel, dim3(1024), dim3(256), 0, stream,
                       Cpart, acc, out, nzbuf);
}

// Round 13
// 178.940 us; speedup vs baseline: 1.0923x; 1.0923x over previous
//
#include <hip/hip_runtime.h>
#include <hip/hip_bf16.h>
#include <math.h>

#define B_N 2048
#define T_N 8192
#define NFFT 4096
#define TF_LEN 4097
#define TOPK 5
#define KSPLIT 4
#define GBK 64

// padded LDS index for float2 Zs array (v6): n + (n>>4) + (n>>8) spreads the
// digit-reversed scatter's 256/512-multiples across bank-pairs; FFT passes
// stay <=2-way. Strictly increasing -> bijective.
#define ZIDX(n) ((n) + ((n) >> 4) + ((n) >> 8))
#define ZPAD (NFFT + (NFFT >> 4) + (NFFT >> 8))  // 4368 float2 slots

typedef float f32x4 __attribute__((ext_vector_type(4)));
typedef __bf16 bf16x8 __attribute__((ext_vector_type(8)));
typedef unsigned short ushort_t;

__device__ __forceinline__ void gload_lds16(const ushort_t* g, ushort_t* l) {
    __builtin_amdgcn_global_load_lds(
        (const __attribute__((address_space(1))) void*)g,
        (__attribute__((address_space(3))) void*)l,
        16, 0, 0);
}

__device__ __forceinline__ float wave_reduce_sum(float v) {
    for (int o = 32; o >= 1; o >>= 1) v += __shfl_xor(v, o, 64);
    return v;
}
__device__ __forceinline__ float wave_reduce_max(float v) {
    for (int o = 32; o >= 1; o >>= 1) v = fmaxf(v, __shfl_xor(v, o, 64));
    return v;
}

__device__ __forceinline__ ushort_t f2bf(float x) {
    __hip_bfloat16 h = __float2bfloat16(x);
    return *reinterpret_cast<ushort_t*>(&h);
}

// native HW trig: input in REVOLUTIONS; cis_rev(r) = (cos(2*pi*r), sin(2*pi*r))
__device__ __forceinline__ float2 cis_rev(float rev) {
    return make_float2(__builtin_amdgcn_cosf(rev), __builtin_amdgcn_sinf(rev));
}
__device__ __forceinline__ float2 cmulf(float2 a, float2 b) {
    return make_float2(a.x * b.x - a.y * b.y, a.x * b.y + a.y * b.x);
}

// binary-power twiddle table: tw[r] = w1^r, depth 4 (was a 15-deep chain).
// All indices static -> registers.
__device__ __forceinline__ void gen_pows(float2 w1, float2 tw[16]) {
    tw[1] = w1;
    tw[2] = cmulf(w1, w1);
    tw[3] = cmulf(tw[2], w1);
    tw[4] = cmulf(tw[2], tw[2]);
    tw[5] = cmulf(tw[4], w1);
    tw[6] = cmulf(tw[4], tw[2]);
    tw[7] = cmulf(tw[4], tw[3]);
    tw[8] = cmulf(tw[4], tw[4]);
    tw[9] = cmulf(tw[8], w1);
    tw[10] = cmulf(tw[8], tw[2]);
    tw[11] = cmulf(tw[8], tw[3]);
    tw[12] = cmulf(tw[8], tw[4]);
    tw[13] = cmulf(tw[8], tw[5]);
    tw[14] = cmulf(tw[8], tw[6]);
    tw[15] = cmulf(tw[8], tw[7]);
}

// ---------------- init: zero acc (+ Cpart when atomic fallback) ----------------
__global__ __launch_bounds__(256) void init_kernel(float* acc, float* Cpart, int nzbuf) {
    if (blockIdx.x == 0 && threadIdx.x < 4) acc[threadIdx.x] = 0.0f;
    if (nzbuf == 1) {
        size_t idx = ((size_t)blockIdx.x * 256 + threadIdx.x) * 4;
        *reinterpret_cast<f32x4*>(&Cpart[idx]) = (f32x4){0.f, 0.f, 0.f, 0.f};
    }
}

// ---------------- DFT16 in registers (two radix-4 levels) ----------------
__device__ __forceinline__ void dft4(float2 x0, float2 x1, float2 x2, float2 x3,
                                     float2* y0, float2* y1, float2* y2, float2* y3) {
    float2 t0 = make_float2(x0.x + x2.x, x0.y + x2.y);
    float2 t1 = make_float2(x0.x - x2.x, x0.y - x2.y);
    float2 t2 = make_float2(x1.x + x3.x, x1.y + x3.y);
    float2 t3 = make_float2(x1.x - x3.x, x1.y - x3.y);
    *y0 = make_float2(t0.x + t2.x, t0.y + t2.y);
    *y2 = make_float2(t0.x - t2.x, t0.y - t2.y);
    *y1 = make_float2(t1.x + t3.y, t1.y - t3.x);   // t1 + (-i)*t3
    *y3 = make_float2(t1.x - t3.y, t1.y + t3.x);   // t1 - (-i)*t3
}

__device__ __forceinline__ void dft16(float2 X[16]) {
    float2 G[16];
    dft4(X[0], X[4], X[8],  X[12], &G[0],  &G[1],  &G[2],  &G[3]);
    dft4(X[1], X[5], X[9],  X[13], &G[4],  &G[5],  &G[6],  &G[7]);
    dft4(X[2], X[6], X[10], X[14], &G[8],  &G[9],  &G[10], &G[11]);
    dft4(X[3], X[7], X[11], X[15], &G[12], &G[13], &G[14], &G[15]);
    const float C1 = 0.9238795325112867f, S1 = 0.3826834323650898f;
    const float R2 = 0.7071067811865476f;
    G[5]  = cmulf(G[5],  make_float2(C1, -S1));   // W^1
    G[6]  = cmulf(G[6],  make_float2(R2, -R2));   // W^2
    G[7]  = cmulf(G[7],  make_float2(S1, -C1));   // W^3
    G[9]  = cmulf(G[9],  make_float2(R2, -R2));   // W^2
    { float2 g = G[10]; G[10] = make_float2(g.y, -g.x); }  // W^4 = -i
    G[11] = cmulf(G[11], make_float2(-R2, -R2));  // W^6
    G[13] = cmulf(G[13], make_float2(S1, -C1));   // W^3
    G[14] = cmulf(G[14], make_float2(-R2, -R2));  // W^6
    G[15] = cmulf(G[15], make_float2(-C1, S1));   // W^9
    dft4(G[0], G[4], G[8],  G[12], &X[0], &X[4], &X[8],  &X[12]);
    dft4(G[1], G[5], G[9],  G[13], &X[1], &X[5], &X[9],  &X[13]);
    dft4(G[2], G[6], G[10], G[14], &X[2], &X[6], &X[10], &X[14]);
    dft4(G[3], G[7], G[11], G[15], &X[3], &X[7], &X[11], &X[15]);
}

// rfft bin from packed-complex spectrum (exact path, used for top bins)
__device__ __forceinline__ void rfft_bin(const float2* Zs, int k, float* orr, float* oi) {
    int kk = k & (NFFT - 1);
    int nk = (NFFT - k) & (NFFT - 1);
    float2 zk = Zs[ZIDX(kk)], znk = Zs[ZIDX(nk)];
    float xer = 0.5f * (zk.x + znk.x);
    float xei = 0.5f * (zk.y - znk.y);
    float xo_r = 0.5f * (zk.y + znk.y);
    float xo_i = -0.5f * (zk.x - znk.x);
    float2 w = cis_rev((float)k * (-1.0f / (float)T_N));
    *orr = xer + w.x * xo_r - w.y * xo_i;
    *oi = xei + w.x * xo_i + w.y * xo_r;
}

// ---------------- fused per-row kernel: prep + ashift + phase ----------------
// v6 (round-9/11 best, 179.2us total): ZIDX bank-spread pad, binary-power
// twiddles, constant-rotor amp, register av[16] + 1-barrier top-5,
// shuffle-Bbf, P_c-decomposed direct DFT. Latency-chain floor ~100us:
// proven insensitive to occupancy/barriers/bank-conflicts (rounds 5-9).
__global__ __launch_bounds__(256) void fused_row_kernel(const float* __restrict__ inp,
                                                        const float* __restrict__ tgt,
                                                        ushort_t* __restrict__ Abf,
                                                        ushort_t* __restrict__ Bbf,
                                                        float* acc) {
    __shared__ float2 Zs[ZPAD];
    __shared__ float red[12];
    __shared__ float wv[2][4];
    __shared__ int wi[2][4];
    __shared__ float2 tgtF[TOPK];
    __shared__ float rscratch[64];

    int b = blockIdx.x;
    int tid = threadIdx.x;
    int lane = tid & 63, wid = tid >> 6;
    const float* tp = tgt + (size_t)b * T_N;
    const float* ip = inp + (size_t)b * T_N;
    ushort_t* Ab = Abf + (size_t)b * T_N;
    ushort_t* Bb = Bbf + (size_t)b * T_N;

    // ---- load tgt: regs + Abf + digit-reversed complex scatter into Zs ----
    float4 trv[8];
#pragma unroll
    for (int i = 0; i < 8; i++) {
        int q = tid + 256 * i;
        trv[i] = *reinterpret_cast<const float4*>(&tp[4 * q]);
        ushort4 ua;
        ua.x = f2bf(trv[i].x); ua.y = f2bf(trv[i].y);
        ua.z = f2bf(trv[i].z); ua.w = f2bf(trv[i].w);
        *reinterpret_cast<ushort4*>(&Ab[4 * q]) = ua;
        int m0 = 2 * q, m1 = 2 * q + 1;
        int p0 = ((m0 & 15) << 8) | (m0 & 0x0F0) | (m0 >> 8);
        int p1 = ((m1 & 15) << 8) | (m1 & 0x0F0) | (m1 >> 8);
        Zs[ZIDX(p0)] = make_float2(trv[i].x, trv[i].y);
        Zs[ZIDX(p1)] = make_float2(trv[i].z, trv[i].w);
    }

    // ---- load inp; d = inp - tgt; Bbf via lane-reversal shuffle ----
    float4 irv[8], dv[8];
#pragma unroll
    for (int i = 0; i < 8; i++) {
        int q = tid + 256 * i;
        irv[i] = *reinterpret_cast<const float4*>(&ip[4 * q]);
        dv[i] = make_float4(irv[i].x - trv[i].x, irv[i].y - trv[i].y,
                            irv[i].z - trv[i].z, irv[i].w - trv[i].w);
        ushort4 ub;
        ub.x = f2bf(-dv[i].w); ub.y = f2bf(-dv[i].z);
        ub.z = f2bf(-dv[i].y); ub.w = f2bf(-dv[i].x);
        uint2 p = *reinterpret_cast<uint2*>(&ub);
        p.x = __shfl_xor(p.x, 63, 64);
        p.y = __shfl_xor(p.y, 63, 64);
        int o = lane + 64 * (31 - wid - 4 * i);
        *reinterpret_cast<uint2*>(&Bb[4 * o]) = p;
    }

    // ---- ashift from d registers (3 barriers via disjoint red slots) ----
    {
        float lmax = -1e30f;
#pragma unroll
        for (int i = 0; i < 8; i++)
            lmax = fmaxf(lmax, fmaxf(fmaxf(dv[i].x, dv[i].y), fmaxf(dv[i].z, dv[i].w)));
        lmax = wave_reduce_max(lmax);
        if (lane == 0) red[wid] = lmax;
        __syncthreads();  // #1: also orders the Zs scatter before FFT pass 0
        float mx = fmaxf(fmaxf(red[0], red[1]), fmaxf(red[2], red[3]));
        float lsum = 0.0f;
#pragma unroll
        for (int i = 0; i < 8; i++) {
            dv[i].x = __expf(dv[i].x - mx);
            dv[i].y = __expf(dv[i].y - mx);
            dv[i].z = __expf(dv[i].z - mx);
            dv[i].w = __expf(dv[i].w - mx);
            lsum += (dv[i].x + dv[i].y) + (dv[i].z + dv[i].w);
        }
        lsum = wave_reduce_sum(lsum);
        if (lane == 0) red[4 + wid] = lsum;
        __syncthreads();  // #2
        float Z = (red[4] + red[5]) + (red[6] + red[7]);
        float inv = 1.0f / Z;
        const float u = 1.0f / (float)T_N;
        float labs = 0.0f;
#pragma unroll
        for (int i = 0; i < 8; i++) {
            labs += fabsf(u - dv[i].x * inv) + fabsf(u - dv[i].y * inv) +
                    fabsf(u - dv[i].z * inv) + fabsf(u - dv[i].w * inv);
        }
        labs = wave_reduce_sum(labs);
        if (lane == 0) red[8 + wid] = labs;
        __syncthreads();  // #3
        if (tid == 0)
            atomicAdd(acc + 0, (red[8] + red[9]) + (red[10] + red[11]));
    }
    // no extra barrier: sync #3 ordered all scatter writes; pass 0 below only
    // reads/writes thread-owned runs after that sync.

    // ---- FFT: 3 radix-16 passes, in place (digit-reversed input) ----
    {  // pass 0: base 16t, stride 1, no twiddle
        float2 X[16];
        int base = tid * 16;
#pragma unroll
        for (int r = 0; r < 16; r++) X[r] = Zs[ZIDX(base + r)];
        dft16(X);
#pragma unroll
        for (int r = 0; r < 16; r++) Zs[ZIDX(base + r)] = X[r];
    }
    __syncthreads();
    {  // pass 1: base = (t>>4)*256 + (t&15), stride 16, twiddle W_256^{j r}
        float2 X[16];
        int j = tid & 15;
        int base = (tid >> 4) * 256 + j;
#pragma unroll
        for (int r = 0; r < 16; r++) X[r] = Zs[ZIDX(base + 16 * r)];
        float2 tw[16];
        gen_pows(cis_rev(-(float)j * (1.0f / 256.0f)), tw);
#pragma unroll
        for (int r = 1; r < 16; r++) X[r] = cmulf(X[r], tw[r]);
        dft16(X);
#pragma unroll
        for (int r = 0; r < 16; r++) Zs[ZIDX(base + 16 * r)] = X[r];
    }
    __syncthreads();
    {  // pass 2: base = t, stride 256, twiddle W_4096^{t r}
        float2 X[16];
#pragma unroll
        for (int r = 0; r < 16; r++) X[r] = Zs[ZIDX(tid + 256 * r)];
        float2 tw[16];
        gen_pows(cis_rev(-(float)tid * (1.0f / 4096.0f)), tw);
#pragma unroll
        for (int r = 1; r < 16; r++) X[r] = cmulf(X[r], tw[r]);
        dft16(X);
#pragma unroll
        for (int r = 0; r < 16; r++) Zs[ZIDX(tid + 256 * r)] = X[r];
    }
    __syncthreads();

    // ---- amplitude^2 of rfft bins -> REGISTERS ----
    // rot_i = rot0 * cis(-i/32): compile-time constants, no serial chain.
    float av[16];
    float aN = -3.0f;  // Nyquist bin 4096, valid on tid 0 only
    {
        const float CC[16] = {
            1.0f, 0.9807852804032304f, 0.9238795325112867f, 0.8314696123025452f,
            0.7071067811865476f, 0.5555702330196022f, 0.3826834323650898f,
            0.1950903220161283f, 0.0f, -0.1950903220161283f, -0.3826834323650898f,
            -0.5555702330196022f, -0.7071067811865476f, -0.8314696123025452f,
            -0.9238795325112867f, -0.9807852804032304f};
        const float SS[16] = {
            0.0f, -0.1950903220161283f, -0.3826834323650898f, -0.5555702330196022f,
            -0.7071067811865476f, -0.8314696123025452f, -0.9238795325112867f,
            -0.9807852804032304f, -1.0f, -0.9807852804032304f, -0.9238795325112867f,
            -0.8314696123025452f, -0.7071067811865476f, -0.5555702330196022f,
            -0.3826834323650898f, -0.1950903220161283f};
        float2 rot0 = cis_rev(-(float)tid * (1.0f / (float)T_N));
#pragma unroll
        for (int i = 0; i < 16; i++) {
            int k = tid + 256 * i;
            if (i == 0 && tid == 0) {
                av[i] = -1.0f;  // DC excluded (reference zeroes bin 0)
            } else {
                float2 rot = cmulf(rot0, make_float2(CC[i], SS[i]));
                int nk = (NFFT - k) & (NFFT - 1);
                float2 zk = Zs[ZIDX(k & (NFFT - 1))], znk = Zs[ZIDX(nk)];
                float xer = 0.5f * (zk.x + znk.x);
                float xei = 0.5f * (zk.y - znk.y);
                float xo_r = 0.5f * (zk.y + znk.y);
                float xo_i = -0.5f * (zk.x - znk.x);
                float xr = xer + rot.x * xo_r - rot.y * xo_i;
                float xi = xei + rot.x * xo_i + rot.y * xo_r;
                av[i] = xr * xr + xi * xi;
            }
        }
        if (tid == 0) {  // Nyquist bin 4096
            float2 z0 = Zs[ZIDX(0)];
            float v = z0.x - z0.y;
            aN = v * v;
        }
    }

    // ---- top-5: 5 argmax rounds over registers, 1 barrier/round ----
    int fqa[TOPK];
#pragma unroll
    for (int r = 0; r < TOPK; r++) {
        float bv = -3.0f;
        int bi = TF_LEN;
#pragma unroll
        for (int i = 0; i < 16; i++) {
            float a = av[i];
            if (a > bv) { bv = a; bi = tid + 256 * i; }
        }
        if (aN > bv) { bv = aN; bi = 4096; }
        for (int o = 1; o < 64; o <<= 1) {
            float ov = __shfl_xor(bv, o, 64);
            int oi = __shfl_xor(bi, o, 64);
            if (ov > bv || (ov == bv && oi < bi)) { bv = ov; bi = oi; }
        }
        if (lane == 0) { wv[r & 1][wid] = bv; wi[r & 1][wid] = bi; }
        __syncthreads();
        float fv = wv[r & 1][0];
        int fi = wi[r & 1][0];
#pragma unroll
        for (int w2 = 1; w2 < 4; w2++) {
            float cv = wv[r & 1][w2];
            int ci = wi[r & 1][w2];
            if (cv > fv || (cv == fv && ci < fi)) { fv = cv; fi = ci; }
        }
        fqa[r] = fi;
        if (fi == 4096) {
            if (tid == 0) aN = -2.0f;
        } else if ((fi & 255) == tid) {
            int slot = fi >> 8;
#pragma unroll
            for (int i = 0; i < 16; i++)
                if (i == slot) av[i] = -2.0f;  // static index (no scratch spill)
        }
    }

    // ---- exact target spectrum at top bins ----
    if (tid < TOPK) {
        int myf = fqa[0];
        if (tid == 1) myf = fqa[1];
        if (tid == 2) myf = fqa[2];
        if (tid == 3) myf = fqa[3];
        if (tid == 4) myf = fqa[4];
        float xr, xi;
        rfft_bin(Zs, myf, &xr, &xi);
        tgtF[tid] = make_float2(xr, xi);
    }
    __syncthreads();

    // ---- direct DFT of input at 5 bins: P_c decomposition ----
    float2 cur[TOPK], wr[TOPK];
    float pre[TOPK][4], pim[TOPK][4];
#pragma unroll
    for (int q = 0; q < TOPK; q++) {
        int f = fqa[q];
        cur[q] = cis_rev(-(float)((f * 4 * tid) & (T_N - 1)) * (1.0f / (float)T_N));
        wr[q] = cis_rev(-(float)((f * 1024) & (T_N - 1)) * (1.0f / (float)T_N));
#pragma unroll
        for (int c = 0; c < 4; c++) { pre[q][c] = 0.0f; pim[q][c] = 0.0f; }
    }
    float E = 0.0f, sev = 0.0f, sod = 0.0f;
#pragma unroll
    for (int i = 0; i < 8; i++) {
        float4 v = irv[i];
        E = fmaf(v.x, v.x, E); sev += v.x;
        E = fmaf(v.y, v.y, E); sod += v.y;
        E = fmaf(v.z, v.z, E); sev += v.z;
        E = fmaf(v.w, v.w, E); sod += v.w;
#pragma unroll
        for (int q = 0; q < TOPK; q++) {
            pre[q][0] = fmaf(v.x, cur[q].x, pre[q][0]);
            pim[q][0] = fmaf(v.x, cur[q].y, pim[q][0]);
            pre[q][1] = fmaf(v.y, cur[q].x, pre[q][1]);
            pim[q][1] = fmaf(v.y, cur[q].y, pim[q][1]);
            pre[q][2] = fmaf(v.z, cur[q].x, pre[q][2]);
            pim[q][2] = fmaf(v.z, cur[q].y, pim[q][2]);
            pre[q][3] = fmaf(v.w, cur[q].x, pre[q][3]);
            pim[q][3] = fmaf(v.w, cur[q].y, pim[q][3]);
            cur[q] = cmulf(cur[q], wr[q]);
        }
    }
    // finalize: res = P0 + W*(P1 + W*(P2 + W*P3)), W = W_8192^f
    float re[TOPK], im[TOPK];
#pragma unroll
    for (int q = 0; q < TOPK; q++) {
        float2 wcq = cis_rev(-(float)fqa[q] * (1.0f / (float)T_N));
        float tr = pre[q][3], ti = pim[q][3];
        float ur = pre[q][2] + (wcq.x * tr - wcq.y * ti);
        float ui = pim[q][2] + (wcq.x * ti + wcq.y * tr);
        float vr = pre[q][1] + (wcq.x * ur - wcq.y * ui);
        float vi = pim[q][1] + (wcq.x * ui + wcq.y * ur);
        re[q] = pre[q][0] + (wcq.x * vr - wcq.y * vi);
        im[q] = pim[q][0] + (wcq.x * vi + wcq.y * vr);
    }

    // ---- block-reduce the 13 scalars and finalize ----
    float vals[13] = {re[0], im[0], re[1], im[1], re[2], im[2], re[3], im[3],
                      re[4], im[4], E, sev + sod, sev - sod};
#pragma unroll
    for (int i = 0; i < 13; i++) {
        float v = wave_reduce_sum(vals[i]);
        if (lane == 0) rscratch[wid * 13 + i] = v;
    }
    __syncthreads();
    if (tid == 0) {
        float tot[13];
        for (int i = 0; i < 13; i++)
            tot[i] = rscratch[i] + rscratch[13 + i] + rscratch[26 + i] + rscratch[39 + i];
        float dsum = 0, isum = 0;
        for (int q = 0; q < TOPK; q++) {
            float rr = tot[2 * q], ii = tot[2 * q + 1];
            float dr = tgtF[q].x - rr, di = tgtF[q].y - ii;
            dsum += dr * dr + di * di;
            isum += rr * rr + ii * ii;
        }
        float Ee = tot[10], X0v = tot[11], Xhv = tot[12];
        float S_all = 0.5f * ((float)T_N * Ee + X0v * X0v + Xhv * Xhv);
        float val = sqrtf(dsum) + sqrtf(fmaxf(S_all - isum, 0.0f));
        atomicAdd(acc + 1, val);
    }
}

// ---------------- GEMM: 256x256 tile, 8-phase counted-vmcnt schedule ----------------
// m201 template port (verified rounds 4-9). KSPLIT=4 plain-stored partials.
// NOTE (rounds 10/12): do NOT fold downstream reductions into epilogues via
// device-scope threadfences — L2 writeback serialization costs 16-90us.
__global__ __launch_bounds__(512, 2) void gemm_kernel(const ushort_t* __restrict__ A,
                                                      const ushort_t* __restrict__ Bm,
                                                      float* __restrict__ Cpart,
                                                      int nzbuf) {
    __shared__ __align__(16) ushort_t lds[2][4][128 * 64];
    int tid = threadIdx.x;
    int bid = blockIdx.x;
    int swz = ((bid & 7) << 5) | (bid >> 3);   // bijective on [0,256): XCD = bid&7
    int bx = swz & 7, by = (swz >> 3) & 7, bz = swz >> 6;
    int row0 = bx * 256, col0 = by * 256;
    const int KC = T_N / KSPLIT;   // 2048
    const int NT = KC / GBK;       // 32
    const int NIT = NT / 2;        // 16
    int kbase = bz * KC;

    int w = tid >> 6, lane = tid & 63;
    int wm = w >> 2, wn = w & 3;   // 2M x 4N waves
    int lr = lane & 15, kq = lane >> 4;

    f32x4 accf[8][4];
#pragma unroll
    for (int mi = 0; mi < 8; mi++)
#pragma unroll
        for (int ni = 0; ni < 4; ni++) accf[mi][ni] = (f32x4){0.f, 0.f, 0.f, 0.f};

    // staging: thread -> (row-in-subhalf, inverse-swizzled col-block)
    int strow = tid >> 3;                 // 0..63
    int scb = (tid & 7) ^ (strow & 7);    // logical 16B col-block
    const ushort_t* gA0 = A + (size_t)(row0 + strow) * T_N + kbase + scb * 8;
    const ushort_t* gA1 = A + (size_t)(row0 + 128 + strow) * T_N + kbase + scb * 8;
    const ushort_t* gB0 = Bm + (size_t)(col0 + strow) * T_N + kbase + scb * 8;
    const ushort_t* gB1 = Bm + (size_t)(col0 + 128 + strow) * T_N + kbase + scb * 8;
    const size_t SUB = (size_t)64 * T_N;  // +64 rows

    // swizzled ds_read bases (ushort units): row*64 + ((cb ^ (row&7))<<3)
    int rb0 = lr * 64 + ((kq ^ (lr & 7)) << 3);        // k-slice 0 (cb = kq)
    int rb1 = lr * 64 + (((4 + kq) ^ (lr & 7)) << 3);  // k-slice 1 (cb = 4+kq)

#define SA_(s, buf, kt)                                                        \
    do {                                                                       \
        gload_lds16(gA0 + (s) * SUB + (size_t)(kt) * GBK, &lds[buf][0][(s) * 4096 + tid * 8]); \
        gload_lds16(gA1 + (s) * SUB + (size_t)(kt) * GBK, &lds[buf][1][(s) * 4096 + tid * 8]); \
    } while (0)
#define SB_(rg, buf, kt)                                                       \
    do {                                                                       \
        const ushort_t* g_ = ((rg) == 2) ? gB0 : gB1;                          \
        gload_lds16(g_ + (size_t)(kt) * GBK, &lds[buf][rg][tid * 8]);          \
        gload_lds16(g_ + SUB + (size_t)(kt) * GBK, &lds[buf][rg][4096 + tid * 8]); \
    } while (0)

#define PHASE(BUF, QM, QN, VMN, STAGE_STMT)                                    \
    do {                                                                       \
        asm volatile("s_waitcnt vmcnt(" #VMN ")" ::: "memory");                \
        const ushort_t* Ab_ = &lds[BUF][wm][0];                                \
        const ushort_t* Bb_ = &lds[BUF][2 + (wn >> 1)][(wn & 1) * 4096];       \
        bf16x8 a_[4][2], b_[2][2];                                             \
        _Pragma("unroll") for (int m_ = 0; m_ < 4; m_++) {                     \
            a_[m_][0] = *reinterpret_cast<const bf16x8*>(Ab_ + (QM) * 4096 + m_ * 1024 + rb0); \
            a_[m_][1] = *reinterpret_cast<const bf16x8*>(Ab_ + (QM) * 4096 + m_ * 1024 + rb1); \
        }                                                                      \
        _Pragma("unroll") for (int n_ = 0; n_ < 2; n_++) {                     \
            b_[n_][0] = *reinterpret_cast<const bf16x8*>(Bb_ + (QN) * 2048 + n_ * 1024 + rb0); \
            b_[n_][1] = *reinterpret_cast<const bf16x8*>(Bb_ + (QN) * 2048 + n_ * 1024 + rb1); \
        }                                                                      \
        STAGE_STMT;                                                            \
        __builtin_amdgcn_s_barrier();                                          \
        __builtin_amdgcn_s_setprio(1);                                         \
        _Pragma("unroll") for (int m_ = 0; m_ < 4; m_++)                       \
        _Pragma("unroll") for (int n_ = 0; n_ < 2; n_++) {                     \
            accf[(QM) * 4 + m_][(QN) * 2 + n_] = __builtin_amdgcn_mfma_f32_16x16x32_bf16( \
                a_[m_][0], b_[n_][0], accf[(QM) * 4 + m_][(QN) * 2 + n_], 0, 0, 0); \
            accf[(QM) * 4 + m_][(QN) * 2 + n_] = __builtin_amdgcn_mfma_f32_16x16x32_bf16( \
                a_[m_][1], b_[n_][1], accf[(QM) * 4 + m_][(QN) * 2 + n_], 0, 0, 0); \
        }                                                                      \
        __builtin_amdgcn_s_setprio(0);                                         \
        __builtin_amdgcn_s_barrier();                                          \
    } while (0)

    // prologue: tile0 fully (A.s0, A.s1, B0, B1) + tile1.A.s0; drain to 2.
    SA_(0, 0, 0);
    SA_(1, 0, 0);
    SB_(2, 0, 0);
    SB_(3, 0, 0);
    SA_(0, 1, 1);
    asm volatile("s_waitcnt vmcnt(2)" ::: "memory");
    __builtin_amdgcn_s_barrier();

    for (int it = 0; it < NIT; ++it) {
        int kt1 = 2 * it + 1;
        int te = (2 * it + 2 < NT) ? 2 * it + 2 : 2 * it;  // even tile (buf0)
        int to = (kt1 + 2 < NT) ? kt1 + 2 : kt1;           // odd tile (buf1)
        PHASE(0, 0, 0, 4, SB_(3, 1, kt1));
        PHASE(0, 0, 1, 4, SB_(2, 1, kt1));
        PHASE(0, 1, 0, 6, SA_(0, 0, te));
        PHASE(0, 1, 1, 2, SA_(1, 1, kt1));
        PHASE(1, 0, 0, 4, SB_(3, 0, te));
        PHASE(1, 0, 1, 2, SB_(2, 0, te));
        PHASE(1, 1, 0, 4, SA_(1, 0, te));
        PHASE(1, 1, 1, 2, SA_(0, 1, to));
    }
#undef PHASE
#undef SA_
#undef SB_

    // epilogue: store partial tile (plain stores; atomic fallback if nzbuf==1)
    int crow = row0 + wm * 128 + (lane >> 4) * 4;
    int ccol = col0 + wn * 64 + lr;
    if (nzbuf == 4) {
        float* Cp = Cpart + (size_t)bz * ((size_t)B_N * B_N);
#pragma unroll
        for (int mi = 0; mi < 8; mi++)
#pragma unroll
            for (int ni = 0; ni < 4; ni++)
#pragma unroll
                for (int r = 0; r < 4; r++)
                    Cp[(size_t)(crow + mi * 16 + r) * B_N + ccol + ni * 16] =
                        accf[mi][ni][r];
    } else {
#pragma unroll
        for (int mi = 0; mi < 8; mi++)
#pragma unroll
            for (int ni = 0; ni < 4; ni++)
#pragma unroll
                for (int r = 0; r < 4; r++)
                    atomicAdd(&Cpart[(size_t)(crow + mi * 16 + r) * B_N + ccol + ni * 16],
                              accf[mi][ni][r]);
    }
}

// ---------------- abs-reduce of summed partials into acc[2] ----------------
__global__ __launch_bounds__(256) void absum_kernel(const float* __restrict__ C,
                                                    float* acc, int nzbuf) {
    __shared__ float sred[4];
    int tid = threadIdx.x;
    int lane = tid & 63, wid = tid >> 6;
    const size_t NN = (size_t)B_N * B_N;
    size_t base = (size_t)blockIdx.x * 4096;  // 1024 blocks x 4096 floats
    float s = 0.0f;
#pragma unroll
    for (int i = 0; i < 4; i++) {
        size_t idx = base + (size_t)(tid + 256 * i) * 4;
        f32x4 v = *reinterpret_cast<const f32x4*>(&C[idx]);
        if (nzbuf == 4) {
            v += *reinterpret_cast<const f32x4*>(&C[NN + idx]);
            v += *reinterpret_cast<const f32x4*>(&C[2 * NN + idx]);
            v += *reinterpret_cast<const f32x4*>(&C[3 * NN + idx]);
        }
        s += fabsf(v.x) + fabsf(v.y) + fabsf(v.z) + fabsf(v.w);
    }
    s = wave_reduce_sum(s);
    if (lane == 0) sred[wid] = s;
    __syncthreads();
    if (tid == 0) atomicAdd(acc + 2, sred[0] + sred[1] + sred[2] + sred[3]);
}

// ---------------- combine ----------------
__global__ void combine_kernel(const float* acc, float* out) {
    if (threadIdx.x == 0) {
        float ash = acc[0] / (float)B_N;
        float ph = acc[1] / (float)B_N;
        float am = acc[2] / ((float)B_N * (float)B_N);
        out[0] = 0.5f * ash + 0.5f * ph + 0.01f * am;
    }
}

extern "C" void kernel_launch(void* const* d_in, const int* in_sizes, int n_in,
                              void* d_out, int out_size, void* d_ws, size_t ws_size,
                              hipStream_t stream) {
    const float* inp = (const float*)d_in[0];
    const float* tgt = (const float*)d_in[1];
    float* acc = (float*)d_ws;
    ushort_t* Abf = (ushort_t*)((char*)d_ws + 256);
    ushort_t* Bbf = Abf + (size_t)B_N * T_N;
    float* Cpart = (float*)(Bbf + (size_t)B_N * T_N);
    float* out = (float*)d_out;

    size_t need4 = 256 + 2 * (size_t)B_N * T_N * sizeof(ushort_t)
                 + (size_t)KSPLIT * (size_t)B_N * B_N * sizeof(float);
    int nzbuf = (ws_size >= need4) ? 4 : 1;

    hipLaunchKernelGGL(init_kernel, dim3(nzbuf == 1 ? 4096 : 1), dim3(256), 0, stream,
                       acc, Cpart, nzbuf);
    hipLaunchKernelGGL(fused_row_kernel, dim3(B_N), dim3(256), 0, stream,
                       inp, tgt, Abf, Bbf, acc);
    hipLaunchKernelGGL(gemm_kernel, dim3(256), dim3(512), 0, stream,
                       Abf, Bbf, Cpart, nzbuf);
    hipLaunchKernelGGL(absum_kernel, dim3(1024), dim3(256), 0, stream,
                       Cpart, acc, nzbuf);
    hipLaunchKernelGGL(combine_kernel, dim3(1), dim3(1), 0, stream, acc, out);
}